// Round 6
// baseline (221.251 us; speedup 1.0000x reference)
//
#include <hip/hip_runtime.h>

#define NDIR  6
#define B_    16
#define N_IN  16384
#define N_OUT 8192
#define IDIM  128
#define ODIM  128
#define TOTAL (B_ * N_OUT)   // 131072 nodes
#define BM    128            // nodes per block (4 waves x 32 rows)

// d_ws layout (ints): [0..7]=cnt, [8..14]=offsets, [16..23]=cursors,
// ids at int 64 (131072 ints), Wt (bf16 hi/lo, pre-swizzled) at int 131584.
#define WS_CNT 0
#define WS_OFF 8
#define WS_CUR 16
#define WS_IDS 64
#define WS_WT  131584

using s16x8 = __attribute__((ext_vector_type(8))) short;   // 8 bf16 (4 VGPR)
using f32x4 = __attribute__((ext_vector_type(4))) float;   // acc frag

__global__ void zero_kernel(int* ws) {
    int t = threadIdx.x;
    if (t < 32) ws[t] = 0;
}

__global__ void count_kernel(const int* __restrict__ vec, const int* __restrict__ dmap,
                             int* __restrict__ ws) {
    __shared__ int h[NDIR];
    int t = threadIdx.x;
    if (t < NDIR) h[t] = 0;
    __syncthreads();
    int id = blockIdx.x * 256 + t;
    if (id < TOTAL) {
        int d = dmap[vec[id]];
        atomicAdd(&h[d], 1);
    }
    __syncthreads();
    if (t < NDIR && h[t]) atomicAdd(&ws[WS_CNT + t], h[t]);
}

__global__ void prefix_kernel(int* ws) {
    if (threadIdx.x == 0) {
        int acc = 0;
        for (int i = 0; i < NDIR; ++i) {
            ws[WS_OFF + i] = acc;
            ws[WS_CUR + i] = acc;
            acc += ws[WS_CNT + i];
        }
        ws[WS_OFF + NDIR] = acc;
    }
}

__global__ void scatter_kernel(const int* __restrict__ vec, const int* __restrict__ dmap,
                               int* __restrict__ ws) {
    __shared__ int h[NDIR];
    __shared__ int base[NDIR];
    int t = threadIdx.x;
    if (t < NDIR) h[t] = 0;
    __syncthreads();
    int id = blockIdx.x * 256 + t;
    int d = 0, pos = 0;
    if (id < TOTAL) {
        d = dmap[vec[id]];
        pos = atomicAdd(&h[d], 1);
    }
    __syncthreads();
    if (t < NDIR) base[t] = h[t] ? atomicAdd(&ws[WS_CUR + t], h[t]) : 0;
    __syncthreads();
    if (id < TOTAL) ws[WS_IDS + base[d] + pos] = id;
}

// Pre-transpose + bf16-split + swizzle W into d_ws.
// Per (dir d, kstep s): 16KB block = hi[col 0..127][chunk' 0..3][i 0..7] bf16
// (8KB) then lo (8KB). Stored chunk position c' holds source chunk c'^key,
// key(col) = (col>>1)&3. So a ds_read at c' = (l>>4)^key returns k-chunk l>>4.
__global__ void wconvert_kernel(const float* __restrict__ W, int* __restrict__ ws) {
    unsigned short* wt = (unsigned short*)(ws + WS_WT);
    int g = blockIdx.x * 256 + threadIdx.x;      // 0..196607
    int dsb = g >> 12;                           // d*8+s, 0..47
    int e = g & 4095;
    int col = e >> 5;
    int kk = e & 31;
    int cp = kk >> 3, i = kk & 7;
    int key = (col >> 1) & 3;
    int d = dsb >> 3, s = dsb & 7;
    int ksrc = s * 32 + ((cp ^ key) << 3) + i;
    float w = W[((d * 256) + ksrc) * 128 + col];
    unsigned u = __float_as_uint(w);
    float hf = __uint_as_float(u & 0xFFFF0000u);
    float lf = w - hf;
    int base = dsb * 8192 + col * 32 + cp * 8 + i;
    wt[base] = (unsigned short)(u >> 16);
    wt[base + 4096] = (unsigned short)(__float_as_uint(lf) >> 16);
}

__device__ __forceinline__ void cvt8(float4 a, float4 b, s16x8& h, s16x8& lo) {
    float x[8] = {a.x, a.y, a.z, a.w, b.x, b.y, b.z, b.w};
    #pragma unroll
    for (int j = 0; j < 8; ++j) {
        unsigned u = __float_as_uint(x[j]);
        float hf = __uint_as_float(u & 0xFFFF0000u);
        float lf = x[j] - hf;
        h[j] = (short)(u >> 16);
        lo[j] = (short)(__float_as_uint(lf) >> 16);
    }
}

// MFMA gather-GEMM: block = 128 nodes x 128 outputs, 4 waves (32 rows each),
// K=256 in 8 steps of 32. fp32 via 3x bf16 MFMA (hh + hl + lh).
// A-gather software-pipelined 1 step ahead; W double-buffered via
// global_load_lds; 4 blocks/CU target.
__global__ __launch_bounds__(256, 4) void gemm_kernel(
    const float* __restrict__ last, const float* __restrict__ bias,
    const float* __restrict__ alphap,
    const int* __restrict__ vec, const int* __restrict__ drev,
    const int* __restrict__ child_l, const int* __restrict__ child_r,
    const int* __restrict__ ws, float* __restrict__ out)
{
    int dir = blockIdx.y;
    int start = ws[WS_OFF + dir];
    int end   = ws[WS_OFF + dir + 1];
    int m0 = start + (int)blockIdx.x * BM;
    if (m0 >= end) return;
    const int* ids = ws + WS_IDS;

    __shared__ unsigned short wbuf[2][8192];   // 2 x 16KB W tiles
    __shared__ int s_row0[BM], s_row1[BM], s_oid[BM];

    int t = threadIdx.x;
    int l = t & 63;
    int wid = t >> 6;

    if (t < BM) {
        int idx = m0 + t;
        bool valid = idx < end;
        int id = ids[valid ? idx : end - 1];
        int b = id >> 13;            // N_OUT = 8192
        int n = id & (N_OUT - 1);
        int v = vec[id];
        int r = drev[v];
        int cl = child_l[n];
        int cr = child_r[n];
        int first  = r ? cr : cl;
        int second = r ? cl : cr;
        s_row0[t] = b * N_IN + first;
        s_row1[t] = b * N_IN + second;
        s_oid[t]  = valid ? id : -1;
    }

    const char* wt_blk = (const char*)(ws + WS_WT) + (size_t)dir * 8 * 16384;

    // stage W kstep `s` into wbuf[buf]: wave wid copies bytes [wid*4K, +4K)
    // as 4 x global_load_lds(16B/lane); LDS dest wave-uniform, linear.
    #define STAGE_W(buf, s_)                                                     \
        {                                                                        \
            const char* gsrc = wt_blk + (size_t)(s_) * 16384 + wid * 4096 + l * 16; \
            char* ldst = (char*)&wbuf[buf][0] + wid * 4096;                      \
            _Pragma("unroll")                                                    \
            for (int i_ = 0; i_ < 4; ++i_) {                                     \
                __builtin_amdgcn_global_load_lds(                                \
                    (const __attribute__((address_space(1))) void*)(gsrc + i_ * 1024), \
                    (__attribute__((address_space(3))) void*)(ldst + i_ * 1024), \
                    16, 0, 0);                                                   \
            }                                                                    \
        }

    STAGE_W(0, 0);
    __syncthreads();   // row-prep + stage(0) visible

    // hoist row indices into registers (address gen no longer waits on LDS)
    int rowA[2][2];
    #pragma unroll
    for (int f = 0; f < 2; ++f) {
        int m = wid * 32 + f * 16 + (l & 15);
        rowA[0][f] = s_row0[m];
        rowA[1][f] = s_row1[m];
    }

    f32x4 acc[2][8];
    #pragma unroll
    for (int f = 0; f < 2; ++f)
        #pragma unroll
        for (int nf = 0; nf < 8; ++nf)
            acc[f][nf] = (f32x4){0.f, 0.f, 0.f, 0.f};

    // prologue: issue A-gather for step 0
    float4 xa0[2], xa1[2];
    #pragma unroll
    for (int f = 0; f < 2; ++f) {
        const float* src = last + (size_t)rowA[0][f] * IDIM + (l >> 4) * 8;
        xa0[f] = *(const float4*)src;
        xa1[f] = *(const float4*)(src + 4);
    }

    #pragma unroll
    for (int s = 0; s < 8; ++s) {
        int cur = s & 1;
        // --- consume prefetched A: convert to bf16 hi/lo
        s16x8 ah[2], al[2];
        #pragma unroll
        for (int f = 0; f < 2; ++f) cvt8(xa0[f], xa1[f], ah[f], al[f]);
        // --- issue A-gather for step s+1 (latency hides under LDS+MFMA+barrier)
        if (s < 7) {
            #pragma unroll
            for (int f = 0; f < 2; ++f) {
                const float* src = last + (size_t)rowA[(s + 1) >> 2][f] * IDIM
                                 + ((s + 1) & 3) * 32 + (l >> 4) * 8;
                xa0[f] = *(const float4*)src;
                xa1[f] = *(const float4*)(src + 4);
            }
        }
        // --- prefetch next W tile (overwrites buffer last read 2 steps ago)
        if (s < 7) STAGE_W(cur ^ 1, s + 1);
        // --- B frags from LDS (swizzled: 2-way max = free)
        s16x8 bh[8], bl[8];
        #pragma unroll
        for (int nf = 0; nf < 8; ++nf) {
            int col = nf * 16 + (l & 15);
            int cp = (l >> 4) ^ ((col >> 1) & 3);
            int off = col * 32 + cp * 8;          // shorts
            bh[nf] = *(const s16x8*)&wbuf[cur][off];
            bl[nf] = *(const s16x8*)&wbuf[cur][off + 4096];
        }
        // --- 3-term split MFMA: 16 frags x 3
        #pragma unroll
        for (int f = 0; f < 2; ++f) {
            #pragma unroll
            for (int nf = 0; nf < 8; ++nf) {
                acc[f][nf] = __builtin_amdgcn_mfma_f32_16x16x32_bf16(ah[f], bh[nf], acc[f][nf], 0, 0, 0);
                acc[f][nf] = __builtin_amdgcn_mfma_f32_16x16x32_bf16(ah[f], bl[nf], acc[f][nf], 0, 0, 0);
                acc[f][nf] = __builtin_amdgcn_mfma_f32_16x16x32_bf16(al[f], bh[nf], acc[f][nf], 0, 0, 0);
            }
        }
        __syncthreads();   // drains stage(next); orders buffer reuse
    }

    // --- epilogue: D frag row=(l>>4)*4+j, col=l&15 (m89/m91 verified)
    float alpha = alphap[0];
    #pragma unroll
    for (int nf = 0; nf < 8; ++nf) {
        int col = nf * 16 + (l & 15);
        float bv = bias[dir * ODIM + col];
        #pragma unroll
        for (int f = 0; f < 2; ++f) {
            #pragma unroll
            for (int j = 0; j < 4; ++j) {
                int mloc = wid * 32 + f * 16 + (l >> 4) * 4 + j;
                int id = s_oid[mloc];
                if (id < 0) continue;
                float y = acc[f][nf][j] + bv;
                out[(size_t)id * ODIM + col] = y >= 0.f ? y : alpha * y;
            }
        }
    }
    #undef STAGE_W
}

extern "C" void kernel_launch(void* const* d_in, const int* in_sizes, int n_in,
                              void* d_out, int out_size, void* d_ws, size_t ws_size,
                              hipStream_t stream) {
    const float* last    = (const float*)d_in[0];
    const float* W       = (const float*)d_in[1];
    const float* bias    = (const float*)d_in[2];
    const float* alpha   = (const float*)d_in[3];
    const int*   vec     = (const int*)d_in[4];
    const int*   dmap    = (const int*)d_in[5];
    const int*   drev    = (const int*)d_in[6];
    const int*   child_l = (const int*)d_in[7];
    const int*   child_r = (const int*)d_in[8];
    float* out = (float*)d_out;
    int*   ws  = (int*)d_ws;

    zero_kernel<<<1, 64, 0, stream>>>(ws);
    count_kernel<<<TOTAL / 256, 256, 0, stream>>>(vec, dmap, ws);
    prefix_kernel<<<1, 64, 0, stream>>>(ws);
    scatter_kernel<<<TOTAL / 256, 256, 0, stream>>>(vec, dmap, ws);
    wconvert_kernel<<<(NDIR * 8 * 4096) / 256, 256, 0, stream>>>(W, ws);
    dim3 grid(TOTAL / BM, NDIR);
    gemm_kernel<<<grid, 256, 0, stream>>>(last, bias, alpha, vec, drev,
                                          child_l, child_r, ws, out);
}

// Round 7
// 85.287 us; speedup vs baseline: 2.5942x; 2.5942x over previous
//
#include <hip/hip_runtime.h>

#define NDIR  6
#define B_    16
#define N_IN  16384
#define N_OUT 8192
#define IDIM  128
#define ODIM  128
#define TOTAL (B_ * N_OUT)   // 131072 nodes
#define BM    128            // nodes per block (4 waves x 32 rows)

// d_ws layout (ints): [0..7]=cnt, [8..14]=offsets, [16..23]=cursors,
// ids at int 64 (131072 ints), Wt (bf16 hi/lo, pre-swizzled) at int 131584.
#define WS_CNT 0
#define WS_OFF 8
#define WS_CUR 16
#define WS_IDS 64
#define WS_WT  131584

using s16x8 = __attribute__((ext_vector_type(8))) short;   // 8 bf16 (4 VGPR)
using f32x4 = __attribute__((ext_vector_type(4))) float;   // acc frag

__global__ void zero_kernel(int* ws) {
    int t = threadIdx.x;
    if (t < 32) ws[t] = 0;
}

__global__ void count_kernel(const int* __restrict__ vec, const int* __restrict__ dmap,
                             int* __restrict__ ws) {
    __shared__ int h[NDIR];
    int t = threadIdx.x;
    if (t < NDIR) h[t] = 0;
    __syncthreads();
    int id = blockIdx.x * 256 + t;
    if (id < TOTAL) {
        int d = dmap[vec[id]];
        atomicAdd(&h[d], 1);
    }
    __syncthreads();
    if (t < NDIR && h[t]) atomicAdd(&ws[WS_CNT + t], h[t]);
}

__global__ void prefix_kernel(int* ws) {
    if (threadIdx.x == 0) {
        int acc = 0;
        for (int i = 0; i < NDIR; ++i) {
            ws[WS_OFF + i] = acc;
            ws[WS_CUR + i] = acc;
            acc += ws[WS_CNT + i];
        }
        ws[WS_OFF + NDIR] = acc;
    }
}

__global__ void scatter_kernel(const int* __restrict__ vec, const int* __restrict__ dmap,
                               int* __restrict__ ws) {
    __shared__ int h[NDIR];
    __shared__ int base[NDIR];
    int t = threadIdx.x;
    if (t < NDIR) h[t] = 0;
    __syncthreads();
    int id = blockIdx.x * 256 + t;
    int d = 0, pos = 0;
    if (id < TOTAL) {
        d = dmap[vec[id]];
        pos = atomicAdd(&h[d], 1);
    }
    __syncthreads();
    if (t < NDIR) base[t] = h[t] ? atomicAdd(&ws[WS_CUR + t], h[t]) : 0;
    __syncthreads();
    if (id < TOTAL) ws[WS_IDS + base[d] + pos] = id;
}

// Pre-transpose + bf16-split + swizzle W into d_ws.
// Per (dir d, kstep s): 16KB block = hi[col 0..127][chunk' 0..3][i 0..7] bf16
// (8KB) then lo (8KB). Stored chunk position c' holds source chunk c'^key,
// key(col) = (col>>1)&3. So a ds_read at c' = (l>>4)^key returns k-chunk l>>4.
__global__ void wconvert_kernel(const float* __restrict__ W, int* __restrict__ ws) {
    unsigned short* wt = (unsigned short*)(ws + WS_WT);
    int g = blockIdx.x * 256 + threadIdx.x;      // 0..196607
    int dsb = g >> 12;                           // d*8+s, 0..47
    int e = g & 4095;
    int col = e >> 5;
    int kk = e & 31;
    int cp = kk >> 3, i = kk & 7;
    int key = (col >> 1) & 3;
    int d = dsb >> 3, s = dsb & 7;
    int ksrc = s * 32 + ((cp ^ key) << 3) + i;
    float w = W[((d * 256) + ksrc) * 128 + col];
    unsigned u = __float_as_uint(w);
    float hf = __uint_as_float(u & 0xFFFF0000u);
    float lf = w - hf;
    int base = dsb * 8192 + col * 32 + cp * 8 + i;
    wt[base] = (unsigned short)(u >> 16);
    wt[base + 4096] = (unsigned short)(__float_as_uint(lf) >> 16);
}

__device__ __forceinline__ void cvt8(float4 a, float4 b, s16x8& h, s16x8& lo) {
    float x[8] = {a.x, a.y, a.z, a.w, b.x, b.y, b.z, b.w};
    #pragma unroll
    for (int j = 0; j < 8; ++j) {
        unsigned u = __float_as_uint(x[j]);
        float hf = __uint_as_float(u & 0xFFFF0000u);
        float lf = x[j] - hf;
        h[j] = (short)(u >> 16);
        lo[j] = (short)(__float_as_uint(lf) >> 16);
    }
}

// MFMA gather-GEMM: block = 128 nodes x 128 outputs, 4 waves (32 rows each),
// K=256 in 8 steps of 32. fp32 via 3x bf16 MFMA (hh + hl + lh).
// A-gather pipelined 1 step ahead; W double-buffered via global_load_lds.
// B-frags consumed in quarters (2 frags live) to keep regs under the
// (256,3) cap (~168): 64 acc + 32 A + 16 B + 16 prefetch + misc ~ 148.
__global__ __launch_bounds__(256, 3) void gemm_kernel(
    const float* __restrict__ last, const float* __restrict__ bias,
    const float* __restrict__ alphap,
    const int* __restrict__ vec, const int* __restrict__ drev,
    const int* __restrict__ child_l, const int* __restrict__ child_r,
    const int* __restrict__ ws, float* __restrict__ out)
{
    int dir = blockIdx.y;
    int start = ws[WS_OFF + dir];
    int end   = ws[WS_OFF + dir + 1];
    int m0 = start + (int)blockIdx.x * BM;
    if (m0 >= end) return;
    const int* ids = ws + WS_IDS;

    __shared__ unsigned short wbuf[2][8192];   // 2 x 16KB W tiles
    __shared__ int s_row0[BM], s_row1[BM], s_oid[BM];

    int t = threadIdx.x;
    int l = t & 63;
    int wid = t >> 6;

    if (t < BM) {
        int idx = m0 + t;
        bool valid = idx < end;
        int id = ids[valid ? idx : end - 1];
        int b = id >> 13;            // N_OUT = 8192
        int n = id & (N_OUT - 1);
        int v = vec[id];
        int r = drev[v];
        int cl = child_l[n];
        int cr = child_r[n];
        int first  = r ? cr : cl;
        int second = r ? cl : cr;
        s_row0[t] = b * N_IN + first;
        s_row1[t] = b * N_IN + second;
        s_oid[t]  = valid ? id : -1;
    }

    const char* wt_blk = (const char*)(ws + WS_WT) + (size_t)dir * 8 * 16384;

    // stage W kstep `s` into wbuf[buf]: wave wid copies bytes [wid*4K, +4K)
    // as 4 x global_load_lds(16B/lane); LDS dest wave-uniform, linear.
    #define STAGE_W(buf, s_)                                                     \
        {                                                                        \
            const char* gsrc = wt_blk + (size_t)(s_) * 16384 + wid * 4096 + l * 16; \
            char* ldst = (char*)&wbuf[buf][0] + wid * 4096;                      \
            _Pragma("unroll")                                                    \
            for (int i_ = 0; i_ < 4; ++i_) {                                     \
                __builtin_amdgcn_global_load_lds(                                \
                    (const __attribute__((address_space(1))) void*)(gsrc + i_ * 1024), \
                    (__attribute__((address_space(3))) void*)(ldst + i_ * 1024), \
                    16, 0, 0);                                                   \
            }                                                                    \
        }

    STAGE_W(0, 0);
    __syncthreads();   // row-prep + stage(0) visible

    // hoist row indices into registers (address gen no longer waits on LDS)
    int rowA[2][2];
    #pragma unroll
    for (int f = 0; f < 2; ++f) {
        int m = wid * 32 + f * 16 + (l & 15);
        rowA[0][f] = s_row0[m];
        rowA[1][f] = s_row1[m];
    }

    f32x4 acc[2][8];
    #pragma unroll
    for (int f = 0; f < 2; ++f)
        #pragma unroll
        for (int nf = 0; nf < 8; ++nf)
            acc[f][nf] = (f32x4){0.f, 0.f, 0.f, 0.f};

    // prologue: issue A-gather for step 0
    float4 xa0[2], xa1[2];
    #pragma unroll
    for (int f = 0; f < 2; ++f) {
        const float* src = last + (size_t)rowA[0][f] * IDIM + (l >> 4) * 8;
        xa0[f] = *(const float4*)src;
        xa1[f] = *(const float4*)(src + 4);
    }

    #pragma unroll
    for (int s = 0; s < 8; ++s) {
        int cur = s & 1;
        // --- consume prefetched A: convert to bf16 hi/lo
        s16x8 ah[2], al[2];
        #pragma unroll
        for (int f = 0; f < 2; ++f) cvt8(xa0[f], xa1[f], ah[f], al[f]);
        // --- issue A-gather for step s+1 (latency hides under LDS+MFMA)
        if (s < 7) {
            #pragma unroll
            for (int f = 0; f < 2; ++f) {
                const float* src = last + (size_t)rowA[(s + 1) >> 2][f] * IDIM
                                 + ((s + 1) & 3) * 32 + (l >> 4) * 8;
                xa0[f] = *(const float4*)src;
                xa1[f] = *(const float4*)(src + 4);
            }
        }
        // --- prefetch next W tile (overwrites buffer last read 2 steps ago)
        if (s < 7) STAGE_W(cur ^ 1, s + 1);
        // --- B frags in quarters: only 2 (bh,bl) pairs live at a time
        #pragma unroll
        for (int q = 0; q < 4; ++q) {
            s16x8 bh[2], bl[2];
            #pragma unroll
            for (int i = 0; i < 2; ++i) {
                int nf = q * 2 + i;
                int col = nf * 16 + (l & 15);
                int cp = (l >> 4) ^ ((col >> 1) & 3);
                int off = col * 32 + cp * 8;          // shorts
                bh[i] = *(const s16x8*)&wbuf[cur][off];
                bl[i] = *(const s16x8*)&wbuf[cur][off + 4096];
            }
            #pragma unroll
            for (int f = 0; f < 2; ++f) {
                #pragma unroll
                for (int i = 0; i < 2; ++i) {
                    int nf = q * 2 + i;
                    acc[f][nf] = __builtin_amdgcn_mfma_f32_16x16x32_bf16(ah[f], bh[i], acc[f][nf], 0, 0, 0);
                    acc[f][nf] = __builtin_amdgcn_mfma_f32_16x16x32_bf16(ah[f], bl[i], acc[f][nf], 0, 0, 0);
                    acc[f][nf] = __builtin_amdgcn_mfma_f32_16x16x32_bf16(al[f], bh[i], acc[f][nf], 0, 0, 0);
                }
            }
        }
        __syncthreads();   // drains stage(next); orders buffer reuse
    }

    // --- epilogue: D frag row=(l>>4)*4+j, col=l&15 (m89/m91 verified)
    float alpha = alphap[0];
    #pragma unroll
    for (int nf = 0; nf < 8; ++nf) {
        int col = nf * 16 + (l & 15);
        float bv = bias[dir * ODIM + col];
        #pragma unroll
        for (int f = 0; f < 2; ++f) {
            #pragma unroll
            for (int j = 0; j < 4; ++j) {
                int mloc = wid * 32 + f * 16 + (l >> 4) * 4 + j;
                int id = s_oid[mloc];
                if (id < 0) continue;
                float y = acc[f][nf][j] + bv;
                out[(size_t)id * ODIM + col] = y >= 0.f ? y : alpha * y;
            }
        }
    }
    #undef STAGE_W
}

extern "C" void kernel_launch(void* const* d_in, const int* in_sizes, int n_in,
                              void* d_out, int out_size, void* d_ws, size_t ws_size,
                              hipStream_t stream) {
    const float* last    = (const float*)d_in[0];
    const float* W       = (const float*)d_in[1];
    const float* bias    = (const float*)d_in[2];
    const float* alpha   = (const float*)d_in[3];
    const int*   vec     = (const int*)d_in[4];
    const int*   dmap    = (const int*)d_in[5];
    const int*   drev    = (const int*)d_in[6];
    const int*   child_l = (const int*)d_in[7];
    const int*   child_r = (const int*)d_in[8];
    float* out = (float*)d_out;
    int*   ws  = (int*)d_ws;

    zero_kernel<<<1, 64, 0, stream>>>(ws);
    count_kernel<<<TOTAL / 256, 256, 0, stream>>>(vec, dmap, ws);
    prefix_kernel<<<1, 64, 0, stream>>>(ws);
    scatter_kernel<<<TOTAL / 256, 256, 0, stream>>>(vec, dmap, ws);
    wconvert_kernel<<<(NDIR * 8 * 4096) / 256, 256, 0, stream>>>(W, ws);
    dim3 grid(TOTAL / BM, NDIR);
    gemm_kernel<<<grid, 256, 0, stream>>>(last, bias, alpha, vec, drev,
                                          child_l, child_r, ws, out);
}